// Round 8
// baseline (147.566 us; speedup 1.0000x reference)
//
#include <hip/hip_runtime.h>
#include <hip/hip_bf16.h>

typedef __bf16 bf16x8 __attribute__((ext_vector_type(8)));
typedef float f32x4 __attribute__((ext_vector_type(4)));

#define N_NODE 50000
#define KPATH 8
#define LPATH 6
#define DNODE 64
#define DPATH 128
#define KDIM 320                 // DNODE*(LPATH-1)
#define N_EDGE 1600000
#define NPAIR (N_NODE * KPATH)   // 400000
#define M_BLK 32
#define NBLK (NPAIR / M_BLK)     // 12500
#define ROW_BYTES 640            // 320 bf16 per row, swizzled
#define WF_BYTES 81920
#define FEATB_BYTES (N_NODE * DNODE * 2)
#define EWB_BYTES (N_EDGE * 2)

// XOR-swizzle: 16B unit moved within its 128B group by row. 640 = 5*128 so
// the XOR (max 112) never crosses a row boundary.
__device__ __forceinline__ int swz(int row, int bytecol) {
    return row * ROW_BYTES + (bytecol ^ ((row & 7) << 4));
}

// Pre-swizzle W (DPATH x KDIM, row-major f32) into bf16 MFMA B-fragment order:
// wf[((nt*10+ks)*64+lane)*8+j] = W[n=nt*16+(lane&15)][k=ks*32+(lane>>4)*8+j]
__global__ void wfrag_prep(const float* __restrict__ W, __bf16* __restrict__ wf) {
    int t = blockIdx.x * 256 + threadIdx.x;
    if (t >= 8 * 10 * 64 * 8) return;
    int j    = t & 7;
    int lane = (t >> 3) & 63;
    int ks   = (t >> 9) % 10;
    int nt   = t / 5120;
    int k = ks * 32 + (lane >> 4) * 8 + j;
    int n = nt * 16 + (lane & 15);
    wf[t] = (__bf16)W[n * KDIM + k];
}

// f32 -> bf16 bulk convert (each thread 8 elements)
__global__ void bf16_prep(const float* __restrict__ f, __bf16* __restrict__ fb, int n8) {
    int t = blockIdx.x * 256 + threadIdx.x;
    if (t >= n8) return;
    float4 a = ((const float4*)f)[t * 2];
    float4 b = ((const float4*)f)[t * 2 + 1];
    union { bf16x8 v; __bf16 e[8]; } u;
    u.e[0] = (__bf16)a.x; u.e[1] = (__bf16)a.y; u.e[2] = (__bf16)a.z; u.e[3] = (__bf16)a.w;
    u.e[4] = (__bf16)b.x; u.e[5] = (__bf16)b.y; u.e[6] = (__bf16)b.z; u.e[7] = (__bf16)b.w;
    ((bf16x8*)fb)[t] = u.v;
}

// MODE: 1 = feat bf16 + weight bf16 ; 0 = all-f32 inline fallback
template <int MODE>
__global__ __launch_bounds__(256, 4) void path_gemm(
    const void*  __restrict__ featv,
    const void*  __restrict__ weightv,
    const int*   __restrict__ paths,
    const int*   __restrict__ eids,
    const __bf16* __restrict__ wf,
    float* __restrict__ out)
{
    __shared__ bf16x8 AsVec[M_BLK * ROW_BYTES / 16];   // 20,480 B
    char* asb = (char*)AsVec;

    const int  t  = threadIdx.x;
    const long p0 = (long)blockIdx.x * M_BLK;
    const int wave = t >> 6;
    const int lane = t & 63;

    // ---------------- stage A tile: gather + combine -> bf16 LDS ----------
    {
        const int  r  = t >> 3;          // row 0..31
        const int  s  = t & 7;           // 16B slice
        const int  d0 = s * 8;
        const int  lr = r & 7;           // row-local index within this wave
        const long p  = p0 + r;

        // Lane-split scalar loads, broadcast to the row's 8 lanes.
        int pv = 0;
        if (s < LPATH) pv = __builtin_nontemporal_load(paths + p * LPATH + s);
        float wv = 0.f;
        if (s < LPATH - 1) {
            int ev = __builtin_nontemporal_load(eids + p * (LPATH - 1) + s);
            wv = MODE ? (float)((const __bf16*)weightv)[ev]
                      : ((const float*)weightv)[ev];
        }

        int idx[LPATH];
#pragma unroll
        for (int l = 0; l < LPATH; ++l) idx[l] = __shfl(pv, lr * 8 + l, 64);
        float ew[LPATH - 1];
#pragma unroll
        for (int l = 0; l < LPATH - 1; ++l) ew[l] = __shfl(wv, lr * 8 + l, 64);

        // Issue ALL 6 row-gathers unconditionally (clamped addr + mask) so
        // the misses overlap instead of serializing 6-deep.
        float msk[LPATH];
        union { bf16x8 v; __bf16 e[8]; } raw[LPATH];
        float4 rawf[LPATH][2];
#pragma unroll
        for (int l = 0; l < LPATH; ++l) {
            const int id = idx[l];
            msk[l] = (id < N_NODE) ? 1.f : 0.f;
            const long off = (long)(id < N_NODE ? id : 0) * DNODE + d0;
            if (MODE) {
                raw[l].v = *(const bf16x8*)((const __bf16*)featv + off);
            } else {
                const float4* sp = (const float4*)((const float*)featv + off);
                rawf[l][0] = sp[0];
                rawf[l][1] = sp[1];
            }
        }

        float x[8];
#pragma unroll
        for (int i = 0; i < 8; ++i)
            x[i] = MODE ? msk[0] * (float)raw[0].e[i]
                        : msk[0] * ((const float*)&rawf[0][0])[i];
#pragma unroll
        for (int l = 1; l < LPATH; ++l) {
            float y[8];
#pragma unroll
            for (int i = 0; i < 8; ++i)
                y[i] = MODE ? msk[l] * (float)raw[l].e[i]
                            : msk[l] * ((const float*)&rawf[l][0])[i];
            union { bf16x8 v; __bf16 e[8]; } u;
#pragma unroll
            for (int i = 0; i < 8; ++i) u.e[i] = (__bf16)(x[i] + ew[l - 1] * y[i]);
            *(bf16x8*)(asb + swz(r, (l - 1) * 128 + s * 16)) = u.v;
#pragma unroll
            for (int i = 0; i < 8; ++i) x[i] = y[i];
        }
    }

    // ---- B fragments: load ONCE per block into VGPRs (kills the 80KB*12500
    //      = 1 GB L2 re-read). Issued before the barrier so the latency
    //      hides under other waves' staging.
    bf16x8 breg[10][2];
#pragma unroll
    for (int ks = 0; ks < 10; ++ks)
#pragma unroll
        for (int nt = 0; nt < 2; ++nt)
            breg[ks][nt] = *(const bf16x8*)(wf + (((wave * 2 + nt) * 10 + ks) * 64 + lane) * 8);

    __syncthreads();

    // ---------------- MFMA: each wave computes 32 rows x 32 cols ----------
    const int lrow = lane & 15;
    const int h    = lane >> 4;

    f32x4 acc[2][2];
#pragma unroll
    for (int mt = 0; mt < 2; ++mt)
#pragma unroll
        for (int nt = 0; nt < 2; ++nt)
            acc[mt][nt] = (f32x4){0.f, 0.f, 0.f, 0.f};

#pragma unroll
    for (int ks = 0; ks < 10; ++ks) {
#pragma unroll
        for (int mt = 0; mt < 2; ++mt) {
            bf16x8 a = *(const bf16x8*)(asb + swz(mt * 16 + lrow, ks * 64 + h * 16));
            acc[mt][0] = __builtin_amdgcn_mfma_f32_16x16x32_bf16(a, breg[ks][0], acc[mt][0], 0, 0, 0);
            acc[mt][1] = __builtin_amdgcn_mfma_f32_16x16x32_bf16(a, breg[ks][1], acc[mt][1], 0, 0, 0);
        }
    }

    // ---------------- epilogue: 4x4 shfl transpose -> float4 nt stores ----
    // acc[mt][nt][q] = C[p0+mt*16+h*4+q][wave*32+nt*16+lrow]. Transpose the
    // 4x4 (lane-group g = lrow&3, reg q) block so each lane stores 4
    // consecutive cols for one row.
    const int g  = lrow & 3;
    const int cg = lrow >> 2;
#pragma unroll
    for (int mt = 0; mt < 2; ++mt) {
#pragma unroll
        for (int nt = 0; nt < 2; ++nt) {
            f32x4 rr = acc[mt][nt];
            // stage 1: 2x2 transpose at bit0 over pairs (0,1) and (2,3)
            float s01 = (g & 1) ? rr[0] : rr[1];
            float s23 = (g & 1) ? rr[2] : rr[3];
            float r01 = __shfl_xor(s01, 1, 64);
            float r23 = __shfl_xor(s23, 1, 64);
            f32x4 aT;
            aT[0] = (g & 1) ? r01 : rr[0];
            aT[1] = (g & 1) ? rr[1] : r01;
            aT[2] = (g & 1) ? r23 : rr[2];
            aT[3] = (g & 1) ? rr[3] : r23;
            // stage 2: 2x2 transpose at bit1 over pairs (0,2) and (1,3)
            float s02 = (g & 2) ? aT[0] : aT[2];
            float s13 = (g & 2) ? aT[1] : aT[3];
            float r02 = __shfl_xor(s02, 2, 64);
            float r13 = __shfl_xor(s13, 2, 64);
            f32x4 w;
            w[0] = (g & 2) ? r02 : aT[0];
            w[2] = (g & 2) ? aT[2] : r02;
            w[1] = (g & 2) ? r13 : aT[1];
            w[3] = (g & 2) ? aT[3] : r13;
            // lane now holds C[p0+mt*16+h*4+g][wave*32+nt*16+cg*4 .. +3]
            long row = p0 + mt * 16 + h * 4 + g;
            int  col = wave * 32 + nt * 16 + cg * 4;
            __builtin_nontemporal_store(w, (f32x4*)&out[row * DPATH + col]);
        }
    }
}

extern "C" void kernel_launch(void* const* d_in, const int* in_sizes, int n_in,
                              void* d_out, int out_size, void* d_ws, size_t ws_size,
                              hipStream_t stream) {
    const float* feat   = (const float*)d_in[0];
    const float* weight = (const float*)d_in[1];
    const float* W      = (const float*)d_in[2];
    const int*   paths  = (const int*)d_in[3];
    const int*   eids   = (const int*)d_in[4];
    float* out = (float*)d_out;

    char* ws = (char*)d_ws;
    __bf16* wf    = (__bf16*)ws;                                   // 81,920 B
    __bf16* featb = (__bf16*)(ws + WF_BYTES);                      // 6,400,000 B
    __bf16* ewb   = (__bf16*)(ws + WF_BYTES + FEATB_BYTES);        // 3,200,000 B

    wfrag_prep<<<160, 256, 0, stream>>>(W, wf);

    if (ws_size >= (size_t)WF_BYTES + FEATB_BYTES + EWB_BYTES) {
        bf16_prep<<<(N_NODE * DNODE / 8 + 255) / 256, 256, 0, stream>>>(feat, featb, N_NODE * DNODE / 8);
        bf16_prep<<<(N_EDGE / 8 + 255) / 256, 256, 0, stream>>>(weight, ewb, N_EDGE / 8);
        path_gemm<1><<<NBLK, 256, 0, stream>>>(featb, ewb, paths, eids, wf, out);
    } else {
        path_gemm<0><<<NBLK, 256, 0, stream>>>(feat, weight, paths, eids, wf, out);
    }
}

// Round 9
// 119.518 us; speedup vs baseline: 1.2347x; 1.2347x over previous
//
#include <hip/hip_runtime.h>
#include <hip/hip_bf16.h>

typedef __bf16 bf16x8 __attribute__((ext_vector_type(8)));
typedef float f32x4 __attribute__((ext_vector_type(4)));

#define N_NODE 50000
#define KPATH 8
#define LPATH 6
#define DNODE 64
#define DPATH 128
#define KDIM 320                 // DNODE*(LPATH-1)
#define N_EDGE 1600000
#define NPAIR (N_NODE * KPATH)   // 400000
#define M_BLK 32
#define NBLK (NPAIR / M_BLK)     // 12500
#define ROW_BYTES 640            // 320 bf16 per row, swizzled
#define WF_BYTES 81920
#define FEATB_BYTES (N_NODE * DNODE * 2)
#define EWB_BYTES (N_EDGE * 2)

// fused-prep block ranges
#define WF_BLKS   160                      // 40960 wf elements
#define FEAT_BLKS 1563                     // 400000 x 8-elem converts
#define WGT_BLKS  782                      // 200000 x 8-elem converts
#define PREP_BLKS (WF_BLKS + FEAT_BLKS + WGT_BLKS)

// XOR-swizzle: 16B unit moved within its 128B group by row. 640 = 5*128 so
// the XOR (max 112) never crosses a row boundary.
__device__ __forceinline__ int swz(int row, int bytecol) {
    return row * ROW_BYTES + (bytecol ^ ((row & 7) << 4));
}

// One launch: W->wf fragment swizzle, feat->bf16, weight->bf16.
__global__ void fused_prep(const float* __restrict__ W, __bf16* __restrict__ wf,
                           const float* __restrict__ feat, __bf16* __restrict__ featb,
                           const float* __restrict__ weight, __bf16* __restrict__ ewb) {
    int b = blockIdx.x;
    if (b < WF_BLKS) {
        int t = b * 256 + threadIdx.x;
        if (t >= 8 * 10 * 64 * 8) return;
        int j    = t & 7;
        int lane = (t >> 3) & 63;
        int ks   = (t >> 9) % 10;
        int nt   = t / 5120;
        int k = ks * 32 + (lane >> 4) * 8 + j;
        int n = nt * 16 + (lane & 15);
        wf[t] = (__bf16)W[n * KDIM + k];
    } else if (b < WF_BLKS + FEAT_BLKS) {
        int t = (b - WF_BLKS) * 256 + threadIdx.x;
        if (t >= N_NODE * DNODE / 8) return;
        float4 a = ((const float4*)feat)[t * 2];
        float4 c = ((const float4*)feat)[t * 2 + 1];
        union { bf16x8 v; __bf16 e[8]; } u;
        u.e[0] = (__bf16)a.x; u.e[1] = (__bf16)a.y; u.e[2] = (__bf16)a.z; u.e[3] = (__bf16)a.w;
        u.e[4] = (__bf16)c.x; u.e[5] = (__bf16)c.y; u.e[6] = (__bf16)c.z; u.e[7] = (__bf16)c.w;
        ((bf16x8*)featb)[t] = u.v;
    } else {
        int t = (b - WF_BLKS - FEAT_BLKS) * 256 + threadIdx.x;
        if (t >= N_EDGE / 8) return;
        float4 a = ((const float4*)weight)[t * 2];
        float4 c = ((const float4*)weight)[t * 2 + 1];
        union { bf16x8 v; __bf16 e[8]; } u;
        u.e[0] = (__bf16)a.x; u.e[1] = (__bf16)a.y; u.e[2] = (__bf16)a.z; u.e[3] = (__bf16)a.w;
        u.e[4] = (__bf16)c.x; u.e[5] = (__bf16)c.y; u.e[6] = (__bf16)c.z; u.e[7] = (__bf16)c.w;
        ((bf16x8*)ewb)[t] = u.v;
    }
}

// MODE: 1 = feat bf16 + weight bf16 ; 0 = all-f32 inline fallback
template <int MODE>
__global__ __launch_bounds__(256) void path_gemm(
    const void*  __restrict__ featv,
    const void*  __restrict__ weightv,
    const int*   __restrict__ paths,
    const int*   __restrict__ eids,
    const __bf16* __restrict__ wf,
    float* __restrict__ out)
{
    __shared__ bf16x8 AsVec[M_BLK * ROW_BYTES / 16];   // 20,480 B
    char* asb = (char*)AsVec;

    const int  t  = threadIdx.x;
    const long p0 = (long)blockIdx.x * M_BLK;
    const int wave = t >> 6;
    const int lane = t & 63;

    // ---- B fragments: load ONCE per block into VGPRs. wf is 80 KB and
    //      L2/L3-hot; issuing first lets the latency overlap the gathers.
    bf16x8 breg[10][2];
#pragma unroll
    for (int ks = 0; ks < 10; ++ks)
#pragma unroll
        for (int nt = 0; nt < 2; ++nt)
            breg[ks][nt] = *(const bf16x8*)(wf + (((wave * 2 + nt) * 10 + ks) * 64 + lane) * 8);

    // ---------------- stage A tile: gather + combine -> bf16 LDS ----------
    {
        const int  r  = t >> 3;          // row 0..31
        const int  s  = t & 7;           // 16B slice
        const int  d0 = s * 8;
        const int  lr = r & 7;           // row-local index within this wave
        const long p  = p0 + r;

        // Lane-split scalar loads, broadcast to the row's 8 lanes.
        int pv = 0;
        if (s < LPATH) pv = __builtin_nontemporal_load(paths + p * LPATH + s);
        float wv = 0.f;
        if (s < LPATH - 1) {
            int ev = __builtin_nontemporal_load(eids + p * (LPATH - 1) + s);
            wv = MODE ? (float)((const __bf16*)weightv)[ev]
                      : ((const float*)weightv)[ev];
        }

        int idx[LPATH];
#pragma unroll
        for (int l = 0; l < LPATH; ++l) idx[l] = __shfl(pv, lr * 8 + l, 64);
        float ew[LPATH - 1];
#pragma unroll
        for (int l = 0; l < LPATH - 1; ++l) ew[l] = __shfl(wv, lr * 8 + l, 64);

        // Issue ALL 6 row-gathers unconditionally (clamped addr + mask) so
        // the misses overlap instead of serializing 6-deep.
        float msk[LPATH];
        union { bf16x8 v; __bf16 e[8]; } raw[LPATH];
        float4 rawf[LPATH][2];
#pragma unroll
        for (int l = 0; l < LPATH; ++l) {
            const int id = idx[l];
            msk[l] = (id < N_NODE) ? 1.f : 0.f;
            const long off = (long)(id < N_NODE ? id : 0) * DNODE + d0;
            if (MODE) {
                raw[l].v = *(const bf16x8*)((const __bf16*)featv + off);
            } else {
                const float4* sp = (const float4*)((const float*)featv + off);
                rawf[l][0] = sp[0];
                rawf[l][1] = sp[1];
            }
        }

        float x[8];
#pragma unroll
        for (int i = 0; i < 8; ++i)
            x[i] = MODE ? msk[0] * (float)raw[0].e[i]
                        : msk[0] * ((const float*)&rawf[0][0])[i];
#pragma unroll
        for (int l = 1; l < LPATH; ++l) {
            float y[8];
#pragma unroll
            for (int i = 0; i < 8; ++i)
                y[i] = MODE ? msk[l] * (float)raw[l].e[i]
                            : msk[l] * ((const float*)&rawf[l][0])[i];
            union { bf16x8 v; __bf16 e[8]; } u;
#pragma unroll
            for (int i = 0; i < 8; ++i) u.e[i] = (__bf16)(x[i] + ew[l - 1] * y[i]);
            *(bf16x8*)(asb + swz(r, (l - 1) * 128 + s * 16)) = u.v;
#pragma unroll
            for (int i = 0; i < 8; ++i) x[i] = y[i];
        }
    }
    __syncthreads();

    // ---------------- MFMA: each wave computes 32 rows x 32 cols ----------
    const int lrow = lane & 15;
    const int h    = lane >> 4;

    f32x4 acc[2][2];
#pragma unroll
    for (int mt = 0; mt < 2; ++mt)
#pragma unroll
        for (int nt = 0; nt < 2; ++nt)
            acc[mt][nt] = (f32x4){0.f, 0.f, 0.f, 0.f};

#pragma unroll
    for (int ks = 0; ks < 10; ++ks) {
#pragma unroll
        for (int mt = 0; mt < 2; ++mt) {
            bf16x8 a = *(const bf16x8*)(asb + swz(mt * 16 + lrow, ks * 64 + h * 16));
            acc[mt][0] = __builtin_amdgcn_mfma_f32_16x16x32_bf16(a, breg[ks][0], acc[mt][0], 0, 0, 0);
            acc[mt][1] = __builtin_amdgcn_mfma_f32_16x16x32_bf16(a, breg[ks][1], acc[mt][1], 0, 0, 0);
        }
    }

    // ---------------- epilogue: nt scalar stores, line-paired order -------
    // For fixed (mt,q) the nt=0 and nt=1 stores cover the SAME 128B line of
    // the same rows (cols w*32..+15 and +16..+31): issue them back-to-back
    // so they merge into full-line writes despite nt.
    const int rbase = h * 4;
#pragma unroll
    for (int mt = 0; mt < 2; ++mt) {
#pragma unroll
        for (int q = 0; q < 4; ++q) {
            long row = p0 + mt * 16 + rbase + q;
            float* rp = &out[row * DPATH + wave * 32 + lrow];
            __builtin_nontemporal_store(acc[mt][0][q], rp);
            __builtin_nontemporal_store(acc[mt][1][q], rp + 16);
        }
    }
}

extern "C" void kernel_launch(void* const* d_in, const int* in_sizes, int n_in,
                              void* d_out, int out_size, void* d_ws, size_t ws_size,
                              hipStream_t stream) {
    const float* feat   = (const float*)d_in[0];
    const float* weight = (const float*)d_in[1];
    const float* W      = (const float*)d_in[2];
    const int*   paths  = (const int*)d_in[3];
    const int*   eids   = (const int*)d_in[4];
    float* out = (float*)d_out;

    char* ws = (char*)d_ws;
    __bf16* wf    = (__bf16*)ws;                                   // 81,920 B
    __bf16* featb = (__bf16*)(ws + WF_BYTES);                      // 6,400,000 B
    __bf16* ewb   = (__bf16*)(ws + WF_BYTES + FEATB_BYTES);        // 3,200,000 B

    if (ws_size >= (size_t)WF_BYTES + FEATB_BYTES + EWB_BYTES) {
        fused_prep<<<PREP_BLKS, 256, 0, stream>>>(W, wf, feat, featb, weight, ewb);
        path_gemm<1><<<NBLK, 256, 0, stream>>>(featb, ewb, paths, eids, wf, out);
    } else {
        fused_prep<<<WF_BLKS, 256, 0, stream>>>(W, wf, feat, featb, weight, ewb);
        path_gemm<0><<<NBLK, 256, 0, stream>>>(feat, weight, paths, eids, wf, out);
    }
}